// Round 6
// baseline (170.238 us; speedup 1.0000x reference)
//
#include <hip/hip_runtime.h>
#include <hip/hip_bf16.h>
#include <math.h>

// HMM forward (logZ), K=64 tags, V=50000, D=128, BATCH=8192, L=126.
// MFMA formulation: alpha_next[16 sent][64 tag] = (alpha x T') .* e_raw[word],
// where T' = softmax(WA) with per-column factor 65536/sumexp[col] folded in
// (BOS/EOS cols = 0). e_raw = exp(E.ThetaB^T) unnormalized. The 2^16/step
// scale keeps alpha in normal f32 range for all 126 steps.
//
// ws layout:
//   [0, 6,400,000)        btn_bf[v][k]  bf16  raw exp(logit)
//   [6,400,000, +16384)   A[i][j]       f32   softmax(WA, col BOS=-inf)+EPS (unscaled)
//   [6,416,384, +256)     sumexp[k]     f32
//   [6,416,640, +200704)  partial[k][784] f32 per-block column sums

#define KT 64
#define VV 50000
#define DD 128
#define BOS_T 62
#define EOS_T 63
#define LLEN 126
#define EPSF 1e-45f
#define SCALE_F 65536.0f
#define LOG_TOTAL_SCALE (2016.0f * 0.6931471805599453f)
#define PITCH 68          // f32 row pitch of LDS alpha tile
#define NBLK 782          // k_emit grid
#define PBLK 784          // padded partial row

#define BTN_OFF   0
#define A_OFF     6400000
#define SUM_OFF   6416384
#define PART_OFF  6416640

typedef short short8 __attribute__((ext_vector_type(8)));
typedef float f32x4  __attribute__((ext_vector_type(4)));

union U8 { short8 v; unsigned u[4]; short s[8]; };

static __device__ inline unsigned short f2bf_u(float x) {
    __hip_bfloat16 h = __float2bfloat16(x);
    return *reinterpret_cast<unsigned short*>(&h);
}
static __device__ inline short f2bf(float x) { return (short)f2bf_u(x); }

// hot-path packed f32->bf16x2: single HW instr on gfx950
#if __has_builtin(__builtin_amdgcn_cvt_pk_bf16_f32)
typedef __bf16 bf16x2 __attribute__((ext_vector_type(2)));
static __device__ inline unsigned pk2(float a, float b) {
    bf16x2 r = __builtin_amdgcn_cvt_pk_bf16_f32(a, b);
    return *reinterpret_cast<unsigned*>(&r);
}
#else
static __device__ inline unsigned pk2(float a, float b) {
    union { float f; unsigned u; } ua, ub;
    ua.f = a; ub.f = b;
    return ((ua.u + 0x8000u) >> 16) | ((ub.u + 0x8000u) & 0xFFFF0000u);
}
#endif
static __device__ inline float lo16(unsigned u) { union { unsigned i; float f; } c; c.i = u << 16;        return c.f; }
static __device__ inline float hi16(unsigned u) { union { unsigned i; float f; } c; c.i = u & 0xffff0000u; return c.f; }

// ---------------------------------------------------------------- A = softmax(WA masked)
__global__ __launch_bounds__(64) void k_prepA(const float* __restrict__ WA,
                                              float* __restrict__ A) {
    int i = blockIdx.x;
    int j = threadIdx.x;
    float wv = WA[i * KT + j];
    float e = (j == BOS_T) ? 0.0f : __expf(wv);
    float s = e;
#pragma unroll
    for (int off = 32; off > 0; off >>= 1) s += __shfl_xor(s, off, 64);
    A[i * KT + j] = e / s + EPSF;
}

// ---------------------------------------------------------------- btn_bf[v][k] = bf16(exp(E[v].ThetaB[k]))  (MFMA GEMM)
__global__ __launch_bounds__(256) void k_emit(const float* __restrict__ ThetaB,
                                              const float* __restrict__ E,
                                              unsigned short* __restrict__ btn_bf,
                                              float* __restrict__ partial) {
    __shared__ float red[4][KT];
    int t    = threadIdx.x;
    int lane = t & 63;
    int w    = t >> 6;
    int n    = lane & 15;
    int q    = lane >> 4;
    int v0   = (blockIdx.x * 4 + w) * 16;

    // A-frags first: E rows are the cold HBM traffic — issue early.
    int rowE = v0 + n; rowE = rowE < VV ? rowE : VV - 1;
    float4 ex[4][2];
#pragma unroll
    for (int kt = 0; kt < 4; ++kt) {
        const float* p = E + (size_t)rowE * DD + kt * 32 + q * 8;
        ex[kt][0] = *(const float4*)p;
        ex[kt][1] = *(const float4*)(p + 4);
    }

    // B-frags: ThetaB^T as B[k=d][n=tag]; frag (kt,nt) reg j = ThetaB[nt*16+n][kt*32+q*8+j]
    short8 Bf[4][4];
#pragma unroll
    for (int kt = 0; kt < 4; ++kt)
#pragma unroll
        for (int nt = 0; nt < 4; ++nt) {
            const float* p = ThetaB + (nt * 16 + n) * DD + kt * 32 + q * 8;
            float4 x = *(const float4*)p;
            float4 y = *(const float4*)(p + 4);
            U8 f;
            f.u[0] = pk2(x.x, x.y); f.u[1] = pk2(x.z, x.w);
            f.u[2] = pk2(y.x, y.y); f.u[3] = pk2(y.z, y.w);
            Bf[kt][nt] = f.v;
        }

    short8 Ae[4];
#pragma unroll
    for (int kt = 0; kt < 4; ++kt) {
        U8 f;
        f.u[0] = pk2(ex[kt][0].x, ex[kt][0].y); f.u[1] = pk2(ex[kt][0].z, ex[kt][0].w);
        f.u[2] = pk2(ex[kt][1].x, ex[kt][1].y); f.u[3] = pk2(ex[kt][1].z, ex[kt][1].w);
        Ae[kt] = f.v;
    }

#pragma unroll
    for (int nt = 0; nt < 4; ++nt) {
        f32x4 C = {0.f, 0.f, 0.f, 0.f};
#pragma unroll
        for (int kt = 0; kt < 4; ++kt)
            C = __builtin_amdgcn_mfma_f32_16x16x32_bf16(Ae[kt], Bf[kt][nt], C, 0, 0, 0);
        float ps = 0.0f;
#pragma unroll
        for (int r = 0; r < 4; ++r) {
            int row = v0 + 4 * q + r;
            float e = __expf(C[r]);
            if (row < VV) {
                btn_bf[(size_t)row * KT + nt * 16 + n] = f2bf_u(e);
                ps += e;
            }
        }
        ps += __shfl_xor(ps, 16, 64);
        ps += __shfl_xor(ps, 32, 64);
        if (q == 0) red[w][nt * 16 + n] = ps;
    }
    __syncthreads();
    if (w == 0) {
        float s = red[0][lane] + red[1][lane] + red[2][lane] + red[3][lane];
        partial[lane * PBLK + blockIdx.x] = s;
    }
}

// ---------------------------------------------------------------- sumexp[k] = sum_blk partial[k][blk]
__global__ __launch_bounds__(256) void k_sum(const float* __restrict__ partial,
                                             float* __restrict__ sumexp) {
    __shared__ float r[4];
    int k = blockIdx.x;
    int t = threadIdx.x;
    float s = 0.0f;
    for (int i = t; i < NBLK; i += 256) s += partial[k * PBLK + i];
#pragma unroll
    for (int off = 32; off > 0; off >>= 1) s += __shfl_xor(s, off, 64);
    if ((t & 63) == 0) r[t >> 6] = s;
    __syncthreads();
    if (t == 0) sumexp[k] = r[0] + r[1] + r[2] + r[3];
}

// ---------------------------------------------------------------- forward scan: 1 wave = 16 sentences, MFMA
__global__ __launch_bounds__(64) void k_fwd(const int* __restrict__ words,
                                            const unsigned short* __restrict__ btn_bf,
                                            const float* __restrict__ A,
                                            const float* __restrict__ sumexp,
                                            float* __restrict__ out) {
    __shared__ __attribute__((aligned(16))) float sh[16 * PITCH];
    int lane = threadIdx.x & 63;
    int n    = lane & 15;     // sentence (read side) / B col
    int q    = lane >> 4;
    int b0   = blockIdx.x * 16;

    // per-column normalization: rs[j] = 65536/sumexp[j], BOS/EOS -> 0 (folds
    // k_norm's table pass into the transition matrix)
    float rs4[4];
#pragma unroll
    for (int nt = 0; nt < 4; ++nt) {
        int col = nt * 16 + n;
        float s = sumexp[col];
        rs4[nt] = (col == BOS_T || col == EOS_T) ? 0.0f : (SCALE_F / s);
    }

    // B-frags of scaled transition T': frag(kt,nt) reg j = T[kt*32+q*8+j][nt*16+n]*rs
    short8 Bf[2][4];
#pragma unroll
    for (int kt = 0; kt < 2; ++kt)
#pragma unroll
        for (int nt = 0; nt < 4; ++nt) {
            U8 f;
#pragma unroll
            for (int j = 0; j < 8; ++j)
                f.s[j] = f2bf(A[(kt * 32 + q * 8 + j) * KT + nt * 16 + n] * rs4[nt]);
            Bf[kt][nt] = f.v;
        }
    // final-step frag: column 0 = A[k][EOS] (unscaled), rest 0
    short8 Bfin[2];
#pragma unroll
    for (int kt = 0; kt < 2; ++kt) {
        U8 f;
#pragma unroll
        for (int j = 0; j < 8; ++j)
            f.s[j] = (n == 0) ? f2bf(A[(kt * 32 + q * 8 + j) * KT + EOS_T]) : (short)0;
        Bfin[kt] = f.v;
    }

    // alpha A-frags (bf16): alpha0 = one-hot at tag 62 -> kt=1, q=3, slot 6
    U8 a0, a1;
#pragma unroll
    for (int j = 0; j < 4; ++j) { a0.u[j] = 0; a1.u[j] = 0; }
    if (q == 3) a1.s[6] = (short)0x3F80;   // bf16(1.0)
    short8 Af0 = a0.v, Af1 = a1.v;

    const int* wrow = words + (size_t)(b0 + n) * LLEN;

    // 3-deep emission prefetch pipeline (random 128B rows from L2/L3)
    int wa = wrow[0], wb = wrow[1], wc = wrow[2];
    uint4 e0a = *(const uint4*)(btn_bf + (size_t)wa * KT + q * 8);
    uint4 e1a = *(const uint4*)(btn_bf + (size_t)wa * KT + 32 + q * 8);
    uint4 e0b = *(const uint4*)(btn_bf + (size_t)wb * KT + q * 8);
    uint4 e1b = *(const uint4*)(btn_bf + (size_t)wb * KT + 32 + q * 8);
    uint4 e0c = *(const uint4*)(btn_bf + (size_t)wc * KT + q * 8);
    uint4 e1c = *(const uint4*)(btn_bf + (size_t)wc * KT + 32 + q * 8);
    int wn = wrow[3];

#pragma unroll 3
    for (int l = 0; l < LLEN; ++l) {
        // issue step-(l+3) prefetch first: no dependents for 3 iterations
        uint4 e0d = *(const uint4*)(btn_bf + (size_t)wn * KT + q * 8);
        uint4 e1d = *(const uint4*)(btn_bf + (size_t)wn * KT + 32 + q * 8);
        int wi = l + 4; wi = wi < LLEN ? wi : LLEN - 1;
        wn = wrow[wi];

        // C[nt] = alpha x T'
        f32x4 C[4];
#pragma unroll
        for (int nt = 0; nt < 4; ++nt) {
            f32x4 acc = {0.f, 0.f, 0.f, 0.f};
            acc = __builtin_amdgcn_mfma_f32_16x16x32_bf16(Af0, Bf[0][nt], acc, 0, 0, 0);
            acc = __builtin_amdgcn_mfma_f32_16x16x32_bf16(Af1, Bf[1][nt], acc, 0, 0, 0);
            C[nt] = acc;
        }

        // write C (f32) to LDS tile [sent m][tag k], m = 4q+r, k = nt*16+n.
        // Same-wave DS ops are processed in order: no s_waitcnt drain needed,
        // only a compiler reorder barrier (round-5's lgkmcnt(0) cost ~100cy/step).
#pragma unroll
        for (int nt = 0; nt < 4; ++nt)
#pragma unroll
            for (int r = 0; r < 4; ++r)
                sh[(4 * q + r) * PITCH + nt * 16 + n] = C[nt][r];
        __builtin_amdgcn_wave_barrier();

        // read back in A-layout (row = sentence n), fold emission, pack bf16
        {
            const float* p = sh + n * PITCH + q * 8;
            float4 lo = *(const float4*)p;
            float4 hi = *(const float4*)(p + 4);
            U8 f;
            f.u[0] = pk2(lo.x * lo16(e0a.x), lo.y * hi16(e0a.x));
            f.u[1] = pk2(lo.z * lo16(e0a.y), lo.w * hi16(e0a.y));
            f.u[2] = pk2(hi.x * lo16(e0a.z), hi.y * hi16(e0a.z));
            f.u[3] = pk2(hi.z * lo16(e0a.w), hi.w * hi16(e0a.w));
            Af0 = f.v;
        }
        {
            const float* p = sh + n * PITCH + 32 + q * 8;
            float4 lo = *(const float4*)p;
            float4 hi = *(const float4*)(p + 4);
            U8 f;
            f.u[0] = pk2(lo.x * lo16(e1a.x), lo.y * hi16(e1a.x));
            f.u[1] = pk2(lo.z * lo16(e1a.y), lo.w * hi16(e1a.y));
            f.u[2] = pk2(hi.x * lo16(e1a.z), hi.y * hi16(e1a.z));
            f.u[3] = pk2(hi.z * lo16(e1a.w), hi.w * hi16(e1a.w));
            Af1 = f.v;
        }
        __builtin_amdgcn_wave_barrier();   // keep next step's writes after these reads
        e0a = e0b; e1a = e1b;
        e0b = e0c; e1b = e1c;
        e0c = e0d; e1c = e1d;
    }

    // logZ = log(sum_j alpha[j] * A[j][EOS]) - total scale
    f32x4 Cf = {0.f, 0.f, 0.f, 0.f};
    Cf = __builtin_amdgcn_mfma_f32_16x16x32_bf16(Af0, Bfin[0], Cf, 0, 0, 0);
    Cf = __builtin_amdgcn_mfma_f32_16x16x32_bf16(Af1, Bfin[1], Cf, 0, 0, 0);
    if (n == 0) {
#pragma unroll
        for (int r = 0; r < 4; ++r)
            out[b0 + 4 * q + r] = logf(Cf[r]) - LOG_TOTAL_SCALE;
    }
}

extern "C" void kernel_launch(void* const* d_in, const int* in_sizes, int n_in,
                              void* d_out, int out_size, void* d_ws, size_t ws_size,
                              hipStream_t stream) {
    const int*   words  = (const int*)d_in[0];     // [8192,126]
    const float* ThetaB = (const float*)d_in[1];   // [64,128]
    const float* WA     = (const float*)d_in[2];   // [64,64]
    const float* E      = (const float*)d_in[3];   // [50000,128]
    float* out = (float*)d_out;                    // [8192]

    char* ws = (char*)d_ws;
    unsigned short* btn_bf = (unsigned short*)(ws + BTN_OFF);
    float* A       = (float*)(ws + A_OFF);
    float* sumexp  = (float*)(ws + SUM_OFF);
    float* partial = (float*)(ws + PART_OFF);

    k_prepA<<<64, 64, 0, stream>>>(WA, A);
    k_emit<<<NBLK, 256, 0, stream>>>(ThetaB, E, btn_bf, partial);
    k_sum<<<KT, 256, 0, stream>>>(partial, sumexp);
    k_fwd<<<8192 / 16, 64, 0, stream>>>(words, btn_bf, A, sumexp, out);
}